// Round 1
// baseline (4397.938 us; speedup 1.0000x reference)
//
#include <hip/hip_runtime.h>
#include <cstdint>
#include <cstddef>

// RNN: B=256, T=512, H=512, I=64, O=24. fp32 in/out.
// Strategy: weight-stationary persistent kernel.
//   grid = 16 blocks x 512 threads (8 waves). Block b owns batch rows [16b,16b+16).
//   W_hh (512x512) lives in VGPRs as MFMA A-fragments: 256 VGPRs/lane (f16).
//   h state lives in LDS (double buffered), broadcast via B-fragment ds_read_b128.
//   Swapped GEMM: C'[hcol x batch] = W_hh[hcol,k] * h_prev^T[k,batch] (mfma 16x16x32 f16).
//   Input proj fused (W_ih frags in regs, x_t staged to LDS, double buffered).
//   Output proj (O=24) round-robin deferred one step: wave (t&7) does step t's
//   output at the top of iteration t+1, reading the same h buffer iteration t+1 reads.
//   One __syncthreads per step.

#define TSTEPS 512
#define HDIM   512
#define NIN    64
#define NOUT   24
#define BB     16    // batch rows per block
#define HPAD   520   // h row pitch (f16) -> conflict-free b128 frag reads (65*16B)
#define XPAD   72    // x row pitch (f16)

typedef _Float16 h16;
typedef __attribute__((ext_vector_type(8))) _Float16 h16x8;
typedef __attribute__((ext_vector_type(4))) _Float16 h16x4;
typedef __attribute__((ext_vector_type(2))) _Float16 h16x2;
typedef __attribute__((ext_vector_type(4))) float    f32x4;
typedef __attribute__((ext_vector_type(2))) float    f32x2;

__device__ __forceinline__ float fast_tanh(float z) {
  // tanh(z) = 1 - 2/(exp2(2z*log2e)+1); robust at +/-inf (e=inf -> 1, e=0 -> -1)
#if __has_builtin(__builtin_amdgcn_exp2f) && __has_builtin(__builtin_amdgcn_rcpf)
  float e = __builtin_amdgcn_exp2f(z * 2.8853900817779268f);
  return 1.0f - 2.0f * __builtin_amdgcn_rcpf(e + 1.0f);
#else
  float e = exp2f(z * 2.8853900817779268f);
  return 1.0f - 2.0f / (e + 1.0f);
#endif
}

// Deferred output projection for step t: out[b0+lr][t][:] = tanh(h_new @ W_ho^T + b_ho)
// hb = h buffer holding the state AFTER step t. A = W_ho from LDS, B = h frags.
// M-tile 0 covers out rows 0..15, M-tile 1 covers 16..31 (24..31 computed on
// in-bounds garbage rows and never stored).
__device__ __forceinline__ void out_proj(
    int t, const h16* __restrict__ hb, const h16* __restrict__ who,
    f32x4 bho0, f32x4 bho1, float* __restrict__ out, int b0, int lr, int lk)
{
  f32x4 o0 = bho0, o1 = bho1;
  const int row1 = (16 + lr < NOUT) ? (16 + lr) : (8 + lr);  // remap OOB rows; results discarded
  #pragma unroll
  for (int s = 0; s < 16; ++s) {
    h16x8 bh = *(const h16x8*)&hb[lr * HPAD + s * 32 + lk * 8];
    h16x8 a0 = *(const h16x8*)&who[lr * HPAD + s * 32 + lk * 8];
    h16x8 a1 = *(const h16x8*)&who[row1 * HPAD + s * 32 + lk * 8];
    o0 = __builtin_amdgcn_mfma_f32_16x16x32_f16(a0, bh, o0, 0, 0, 0);
    o1 = __builtin_amdgcn_mfma_f32_16x16x32_f16(a1, bh, o1, 0, 0, 0);
  }
  // C layout: col = lane&15 = batch row, rows = 4*lk + i = out channel
  float* op = out + ((size_t)(b0 + lr) * TSTEPS + t) * NOUT;
  f32x4 v0;
  #pragma unroll
  for (int i = 0; i < 4; ++i) v0[i] = fast_tanh(o0[i]);
  *(f32x4*)(op + lk * 4) = v0;
  if (lk < 2) {  // out channels 16+4*lk .. 16+4*lk+3 (<24) valid only for lk<2
    f32x4 v1;
    #pragma unroll
    for (int i = 0; i < 4; ++i) v1[i] = fast_tanh(o1[i]);
    *(f32x4*)(op + 16 + lk * 4) = v1;
  }
}

__global__ __launch_bounds__(512, 2)
void rnn_fused(const float* __restrict__ x,
               const float* __restrict__ Wih,
               const float* __restrict__ Whh,
               const float* __restrict__ bih,
               const float* __restrict__ bhh,
               const float* __restrict__ Who,
               const float* __restrict__ bho,
               float* __restrict__ out)
{
  __shared__ h16 hbuf[2][BB * HPAD];      // 33280 B  h state, [batch_row][hcol]
  __shared__ h16 xbuf[2][BB * XPAD];      //  4608 B  x_t tile, [batch_row][i]
  __shared__ h16 wholds[NOUT * HPAD];     // 24960 B  W_ho, [o][k]
                                          // total 62848 B < 64 KiB

  const int tid  = threadIdx.x;
  const int wave = tid >> 6;
  const int lane = tid & 63;
  const int lr   = lane & 15;   // A-frag row / B-frag col index
  const int lk   = lane >> 4;   // k-group (0..3)
  const int b0   = blockIdx.x * BB;
  const int wc0  = wave * 64;   // this wave's h-column base (owns 64 of 512 cols)

  // ---- persistent register fragments ----
  // A-frag (16x32, f16): lane holds A[row = lane&15][k = (lane>>4)*8 + j], j=0..7
  h16x8 a_rec[4][16];   // W_hh rows wc0+m*16+lr, 16 K-steps  -> 256 VGPRs
  #pragma unroll
  for (int m = 0; m < 4; ++m) {
    const int row = wc0 + m * 16 + lr;
    #pragma unroll
    for (int s = 0; s < 16; ++s) {
      const float* p = Whh + (size_t)row * HDIM + s * 32 + lk * 8;
      f32x4 f0 = *(const f32x4*)p;
      f32x4 f1 = *(const f32x4*)(p + 4);
      h16x8 a;
      #pragma unroll
      for (int j = 0; j < 4; ++j) { a[j] = (h16)f0[j]; a[4 + j] = (h16)f1[j]; }
      a_rec[m][s] = a;
    }
  }
  h16x8 a_ih[4][2];     // W_ih frags -> 32 VGPRs
  #pragma unroll
  for (int m = 0; m < 4; ++m) {
    const int row = wc0 + m * 16 + lr;
    #pragma unroll
    for (int s = 0; s < 2; ++s) {
      const float* p = Wih + (size_t)row * NIN + s * 32 + lk * 8;
      f32x4 f0 = *(const f32x4*)p;
      f32x4 f1 = *(const f32x4*)(p + 4);
      h16x8 a;
      #pragma unroll
      for (int j = 0; j < 4; ++j) { a[j] = (h16)f0[j]; a[4 + j] = (h16)f1[j]; }
      a_ih[m][s] = a;
    }
  }
  // acc init = b_ih + b_hh at cols wc0 + m*16 + 4*lk + i (C layout rows)
  f32x4 biasv[4];
  #pragma unroll
  for (int m = 0; m < 4; ++m) {
    const int c = wc0 + m * 16 + lk * 4;
    f32x4 bi = *(const f32x4*)&bih[c];
    f32x4 bh2 = *(const f32x4*)&bhh[c];
    biasv[m] = bi + bh2;
  }
  // b_ho for out-proj (lanes mapping to o>=24 get zeros; never stored)
  f32x4 bho0, bho1;
  { int ob = lk * 4;      bho0 = *(const f32x4*)&bho[ob]; }
  { int ob = 16 + lk * 4;
    if (ob < NOUT) bho1 = *(const f32x4*)&bho[ob];
    else { bho1[0] = 0.f; bho1[1] = 0.f; bho1[2] = 0.f; bho1[3] = 0.f; } }

  // ---- stage W_ho to LDS, zero h0, stage x(t=0) ----
  for (int idx = tid; idx < NOUT * HDIM; idx += 512) {
    int r = idx >> 9, k = idx & 511;
    wholds[r * HPAD + k] = (h16)Who[idx];
  }
  for (int idx = tid; idx < BB * HPAD; idx += 512) hbuf[0][idx] = (h16)0.f;
  {
    int r = tid >> 5, c2 = (tid & 31) * 2;
    f32x2 v = *(const f32x2*)(x + ((size_t)(b0 + r) * TSTEPS + 0) * NIN + c2);
    h16x2 pk = { (h16)v.x, (h16)v.y };
    *(h16x2*)&xbuf[0][r * XPAD + c2] = pk;
  }
  __syncthreads();

  // ---- main recurrence ----
  for (int t = 0; t < TSTEPS; ++t) {
    const h16* hb = hbuf[t & 1];         // h after step t-1
    h16*       hn = hbuf[(t + 1) & 1];
    const h16* xb = xbuf[t & 1];
    h16*       xn = xbuf[(t + 1) & 1];

    // deferred output for step t-1 (reads same buffer this iteration reads)
    if (t > 0 && wave == ((t - 1) & 7)) {
      out_proj(t - 1, hb, wholds, bho0, bho1, out, b0, lr, lk);
    }

    // prefetch x(t+1) to registers (latency hidden under MFMAs)
    const int tl = (t + 1 < TSTEPS) ? (t + 1) : (TSTEPS - 1);
    const int xr = tid >> 5, xc = (tid & 31) * 2;
    f32x2 xv = *(const f32x2*)(x + ((size_t)(b0 + xr) * TSTEPS + tl) * NIN + xc);

    // z = bias + W_ih x_t + W_hh h_prev   (C'[hcol x batch])
    f32x4 acc[4];
    #pragma unroll
    for (int m = 0; m < 4; ++m) acc[m] = biasv[m];
    #pragma unroll
    for (int s = 0; s < 2; ++s) {
      h16x8 bx = *(const h16x8*)&xb[lr * XPAD + s * 32 + lk * 8];
      #pragma unroll
      for (int m = 0; m < 4; ++m)
        acc[m] = __builtin_amdgcn_mfma_f32_16x16x32_f16(a_ih[m][s], bx, acc[m], 0, 0, 0);
    }
    #pragma unroll
    for (int s = 0; s < 16; ++s) {
      h16x8 bh = *(const h16x8*)&hb[lr * HPAD + s * 32 + lk * 8];
      #pragma unroll
      for (int m = 0; m < 4; ++m)
        acc[m] = __builtin_amdgcn_mfma_f32_16x16x32_f16(a_rec[m][s], bh, acc[m], 0, 0, 0);
    }

    // h_new = tanh(z); C layout: lane -> batch row lr, hcols wc0+m*16+4*lk+i
    // 4 consecutive f16 -> one ds_write_b64
    #pragma unroll
    for (int m = 0; m < 4; ++m) {
      h16x4 hv;
      #pragma unroll
      for (int i = 0; i < 4; ++i) hv[i] = (h16)fast_tanh(acc[m][i]);
      *(h16x4*)&hn[lr * HPAD + wc0 + m * 16 + lk * 4] = hv;
    }

    // commit x(t+1) tile
    {
      h16x2 pk = { (h16)xv.x, (h16)xv.y };
      *(h16x2*)&xn[xr * XPAD + xc] = pk;
    }

    __syncthreads();
  }

  // final deferred output (t = 511), state is in hbuf[0]
  if (wave == ((TSTEPS - 1) & 7)) {
    out_proj(TSTEPS - 1, hbuf[(TSTEPS) & 1], wholds, bho0, bho1, out, b0, lr, lk);
  }
}

extern "C" void kernel_launch(void* const* d_in, const int* in_sizes, int n_in,
                              void* d_out, int out_size, void* d_ws, size_t ws_size,
                              hipStream_t stream) {
  (void)in_sizes; (void)n_in; (void)d_ws; (void)ws_size; (void)out_size;
  const float* x   = (const float*)d_in[0];
  const float* Wih = (const float*)d_in[1];
  const float* Whh = (const float*)d_in[2];
  const float* bih = (const float*)d_in[3];
  const float* bhh = (const float*)d_in[4];
  const float* Who = (const float*)d_in[5];
  const float* bho = (const float*)d_in[6];
  float* out = (float*)d_out;

  rnn_fused<<<dim3(256 / BB), dim3(512), 0, stream>>>(x, Wih, Whh, bih, bhh, Who, bho, out);
}

// Round 2
// 1943.673 us; speedup vs baseline: 2.2627x; 2.2627x over previous
//
#include <hip/hip_runtime.h>
#include <cstdint>
#include <cstddef>

// RNN: B=256, T=512, H=512, I=64, O=24. fp32 in/out.
//
// Fast path (needs ws_size >= 128 MiB):
//   Prologue kernel xp_gemm: xp[b][t][:] = W_ih x[b][t] + b_ih + b_hh, stored
//   f16 in d_ws PERMUTED so each main-kernel lane reads one 32 B chunk/step.
//   Main kernel rnn_fast: 16 blocks x 512 thr (8 waves), block owns 16 batch
//   rows. W_hh f16 as MFMA A-frags: 50 fragment slots in VGPRs (200 regs) +
//   14 slots in LDS (112 KB) -- W_hh = 512 KB = the entire CU register file,
//   so full-register residency is impossible (round-0 spilled; VGPR=128).
//   h single-buffered in LDS (2 barriers/step). Out-proj round-robin deferred.
// Fallback path: round-0 kernel (correct, ~4.4 ms).

#define TSTEPS 512
#define HDIM   512
#define NIN    64
#define NOUT   24
#define BB     16
#define HPAD   520
#define XPAD   72
#define NREG   50          // a_rec slots in registers (of 64); rest in LDS
#define NLDS   (64 - NREG)

typedef _Float16 h16;
typedef __attribute__((ext_vector_type(8))) _Float16 h16x8;
typedef __attribute__((ext_vector_type(4))) _Float16 h16x4;
typedef __attribute__((ext_vector_type(2))) _Float16 h16x2;
typedef __attribute__((ext_vector_type(4))) float    f32x4;
typedef __attribute__((ext_vector_type(2))) float    f32x2;

__device__ __forceinline__ float fast_tanh(float z) {
  float e = __builtin_amdgcn_exp2f(z * 2.8853900817779268f);
  return 1.0f - 2.0f * __builtin_amdgcn_rcpf(e + 1.0f);
}

__device__ __forceinline__ h16x8 cvt8(const float* __restrict__ p) {
  f32x4 f0 = *(const f32x4*)p;
  f32x4 f1 = *(const f32x4*)(p + 4);
  h16x8 a;
  #pragma unroll
  for (int j = 0; j < 4; ++j) { a[j] = (h16)f0[j]; a[4 + j] = (h16)f1[j]; }
  return a;
}

// Deferred output projection for step t (validated in round 0).
__device__ __forceinline__ void out_proj(
    int t, const h16* __restrict__ hb, const h16* __restrict__ who,
    f32x4 bho0, f32x4 bho1, float* __restrict__ out, int b0, int lr, int lk)
{
  f32x4 o0 = bho0, o1 = bho1;
  const int row1 = (16 + lr < NOUT) ? (16 + lr) : (8 + lr);
  #pragma unroll
  for (int s = 0; s < 16; ++s) {
    h16x8 bh = *(const h16x8*)&hb[lr * HPAD + s * 32 + lk * 8];
    h16x8 a0 = *(const h16x8*)&who[lr * HPAD + s * 32 + lk * 8];
    h16x8 a1 = *(const h16x8*)&who[row1 * HPAD + s * 32 + lk * 8];
    o0 = __builtin_amdgcn_mfma_f32_16x16x32_f16(a0, bh, o0, 0, 0, 0);
    o1 = __builtin_amdgcn_mfma_f32_16x16x32_f16(a1, bh, o1, 0, 0, 0);
  }
  float* op = out + ((size_t)(b0 + lr) * TSTEPS + t) * NOUT;
  f32x4 v0;
  #pragma unroll
  for (int i = 0; i < 4; ++i) v0[i] = fast_tanh(o0[i]);
  *(f32x4*)(op + lk * 4) = v0;
  if (lk < 2) {
    f32x4 v1;
    #pragma unroll
    for (int i = 0; i < 4; ++i) v1[i] = fast_tanh(o1[i]);
    *(f32x4*)(op + 16 + lk * 4) = v1;
  }
}

// ---------------- Prologue: xp = W_ih x + b_ih + b_hh, permuted f16 ----------
// chunk index: ((t*16 + blk)*8 + wave)*64 + lane, 16 f16 per chunk:
// chunk[m*4+i] = xp[batch=16*blk+(lane&15)][t][col=64*wave+16*m+4*(lane>>4)+i]
__global__ __launch_bounds__(512)
void xp_gemm(const float* __restrict__ x, const float* __restrict__ Wih,
             const float* __restrict__ bih, const float* __restrict__ bhh,
             h16* __restrict__ xp)
{
  const int tid  = threadIdx.x;
  const int wave = tid >> 6;
  const int lane = tid & 63;
  const int lr   = lane & 15;
  const int lk   = lane >> 4;
  const int blk  = blockIdx.x & 15;
  const int tc   = blockIdx.x >> 4;
  const int c0   = wave * 64;

  h16x8 A[4][2];
  #pragma unroll
  for (int m = 0; m < 4; ++m)
    #pragma unroll
    for (int s = 0; s < 2; ++s)
      A[m][s] = cvt8(Wih + (size_t)(c0 + 16 * m + lr) * NIN + 32 * s + 8 * lk);

  f32x4 bias[4];
  #pragma unroll
  for (int m = 0; m < 4; ++m) {
    const int c = c0 + 16 * m + 4 * lk;
    f32x4 bi = *(const f32x4*)&bih[c];
    f32x4 bh = *(const f32x4*)&bhh[c];
    bias[m] = bi + bh;
  }

  const float* xrow = x + (size_t)(16 * blk + lr) * (TSTEPS * NIN);

  for (int j = 0; j < 32; ++j) {
    const int t = tc * 32 + j;
    f32x4 acc[4];
    #pragma unroll
    for (int m = 0; m < 4; ++m) acc[m] = bias[m];
    #pragma unroll
    for (int s = 0; s < 2; ++s) {
      h16x8 bx = cvt8(xrow + (size_t)t * NIN + 32 * s + 8 * lk);
      #pragma unroll
      for (int m = 0; m < 4; ++m)
        acc[m] = __builtin_amdgcn_mfma_f32_16x16x32_f16(A[m][s], bx, acc[m], 0, 0, 0);
    }
    h16x8 c0v, c1v;
    #pragma unroll
    for (int i = 0; i < 4; ++i) {
      c0v[i]     = (h16)acc[0][i];
      c0v[4 + i] = (h16)acc[1][i];
      c1v[i]     = (h16)acc[2][i];
      c1v[4 + i] = (h16)acc[3][i];
    }
    h16* p = xp + ((((size_t)t * 16 + blk) * 8 + wave) * 64 + lane) * 16;
    *(h16x8*)p       = c0v;
    *(h16x8*)(p + 8) = c1v;
  }
}

// ---------------- Fast main kernel -------------------------------------------
__global__ void __launch_bounds__(512) __attribute__((amdgpu_waves_per_eu(2, 2)))
rnn_fast(const float* __restrict__ Whh, const float* __restrict__ Who,
         const float* __restrict__ bho, const h16* __restrict__ xp,
         float* __restrict__ out)
{
  __shared__ h16 hls[BB * HPAD];             // 16640 B, single-buffered h
  __shared__ h16 wholds[NOUT * HPAD];        // 24960 B
  __shared__ h16 aslice[NLDS * 8 * 512];     // 114688 B: [slot][wave][512 h16]
                                             // total 156288 B < 160 KiB

  const int tid  = threadIdx.x;
  const int wave = tid >> 6;
  const int lane = tid & 63;
  const int lr   = lane & 15;
  const int lk   = lane >> 4;
  const int blk  = blockIdx.x;
  const int b0   = blk * BB;
  const int wc0  = wave * 64;

  // ---- W_hh fragments: slots id = s*4+m; id < NREG -> regs, else LDS ----
  h16x8 areg[NREG];
  #pragma unroll
  for (int s = 0; s < 16; ++s) {
    #pragma unroll
    for (int m = 0; m < 4; ++m) {
      h16x8 a = cvt8(Whh + (size_t)(wc0 + 16 * m + lr) * HDIM + 32 * s + 8 * lk);
      const int id = s * 4 + m;
      if (id < NREG) areg[id] = a;
      else *(h16x8*)&aslice[(size_t)((id - NREG) * 8 + wave) * 512 + lane * 8] = a;
    }
  }

  f32x4 bho0, bho1;
  { bho0 = *(const f32x4*)&bho[lk * 4]; }
  { int ob = 16 + lk * 4;
    if (ob < NOUT) bho1 = *(const f32x4*)&bho[ob];
    else { bho1[0] = 0.f; bho1[1] = 0.f; bho1[2] = 0.f; bho1[3] = 0.f; } }

  for (int idx = tid; idx < NOUT * HDIM; idx += 512) {
    int r = idx >> 9, k = idx & 511;
    wholds[r * HPAD + k] = (h16)Who[idx];
  }
  for (int idx = tid; idx < BB * HPAD; idx += 512) hls[idx] = (h16)0.f;
  __syncthreads();

  // preload xp(0)
  h16x8 xr0, xr1;
  {
    const h16* p = xp + (((size_t)blk * 8 + wave) * 64 + lane) * 16;
    xr0 = *(const h16x8*)p;
    xr1 = *(const h16x8*)(p + 8);
  }

  for (int t = 0; t < TSTEPS; ++t) {
    // deferred output for step t-1 (hls still holds h(t-1))
    if (t > 0 && wave == ((t - 1) & 7)) {
      out_proj(t - 1, hls, wholds, bho0, bho1, out, b0, lr, lk);
    }

    // acc init from prefetched xp(t)
    f32x4 acc[4];
    #pragma unroll
    for (int i = 0; i < 4; ++i) {
      acc[0][i] = (float)xr0[i];
      acc[1][i] = (float)xr0[4 + i];
      acc[2][i] = (float)xr1[i];
      acc[3][i] = (float)xr1[4 + i];
    }

    // prefetch xp(t+1)
    {
      const int tn = (t + 1 < TSTEPS) ? (t + 1) : t;
      const h16* p = xp + ((((size_t)tn * 16 + blk) * 8 + wave) * 64 + lane) * 16;
      xr0 = *(const h16x8*)p;
      xr1 = *(const h16x8*)(p + 8);
    }

    // z += W_hh h_prev
    #pragma unroll
    for (int s = 0; s < 16; ++s) {
      h16x8 bh = *(const h16x8*)&hls[lr * HPAD + 32 * s + 8 * lk];
      #pragma unroll
      for (int m = 0; m < 4; ++m) {
        const int id = s * 4 + m;
        h16x8 a = (id < NREG)
            ? areg[id]
            : *(const h16x8*)&aslice[(size_t)((id - NREG) * 8 + wave) * 512 + lane * 8];
        acc[m] = __builtin_amdgcn_mfma_f32_16x16x32_f16(a, bh, acc[m], 0, 0, 0);
      }
    }

    __syncthreads();   // all reads of hls (incl. out_proj's) complete

    #pragma unroll
    for (int m = 0; m < 4; ++m) {
      h16x4 hv;
      #pragma unroll
      for (int i = 0; i < 4; ++i) hv[i] = (h16)fast_tanh(acc[m][i]);
      *(h16x4*)&hls[lr * HPAD + wc0 + 16 * m + 4 * lk] = hv;
    }

    __syncthreads();   // h(t) visible to all
  }

  if (wave == ((TSTEPS - 1) & 7)) {
    out_proj(TSTEPS - 1, hls, wholds, bho0, bho1, out, b0, lr, lk);
  }
}

// ---------------- Fallback: round-0 kernel (correct, slow) -------------------
__global__ __launch_bounds__(512, 2)
void rnn_fused(const float* __restrict__ x,
               const float* __restrict__ Wih,
               const float* __restrict__ Whh,
               const float* __restrict__ bih,
               const float* __restrict__ bhh,
               const float* __restrict__ Who,
               const float* __restrict__ bho,
               float* __restrict__ out)
{
  __shared__ h16 hbuf[2][BB * HPAD];
  __shared__ h16 xbuf[2][BB * XPAD];
  __shared__ h16 wholds[NOUT * HPAD];

  const int tid  = threadIdx.x;
  const int wave = tid >> 6;
  const int lane = tid & 63;
  const int lr   = lane & 15;
  const int lk   = lane >> 4;
  const int b0   = blockIdx.x * BB;
  const int wc0  = wave * 64;

  h16x8 a_rec[4][16];
  #pragma unroll
  for (int m = 0; m < 4; ++m) {
    const int row = wc0 + m * 16 + lr;
    #pragma unroll
    for (int s = 0; s < 16; ++s)
      a_rec[m][s] = cvt8(Whh + (size_t)row * HDIM + s * 32 + lk * 8);
  }
  h16x8 a_ih[4][2];
  #pragma unroll
  for (int m = 0; m < 4; ++m) {
    const int row = wc0 + m * 16 + lr;
    #pragma unroll
    for (int s = 0; s < 2; ++s)
      a_ih[m][s] = cvt8(Wih + (size_t)row * NIN + s * 32 + lk * 8);
  }
  f32x4 biasv[4];
  #pragma unroll
  for (int m = 0; m < 4; ++m) {
    const int c = wc0 + m * 16 + lk * 4;
    f32x4 bi = *(const f32x4*)&bih[c];
    f32x4 bh2 = *(const f32x4*)&bhh[c];
    biasv[m] = bi + bh2;
  }
  f32x4 bho0, bho1;
  { bho0 = *(const f32x4*)&bho[lk * 4]; }
  { int ob = 16 + lk * 4;
    if (ob < NOUT) bho1 = *(const f32x4*)&bho[ob];
    else { bho1[0] = 0.f; bho1[1] = 0.f; bho1[2] = 0.f; bho1[3] = 0.f; } }

  for (int idx = tid; idx < NOUT * HDIM; idx += 512) {
    int r = idx >> 9, k = idx & 511;
    wholds[r * HPAD + k] = (h16)Who[idx];
  }
  for (int idx = tid; idx < BB * HPAD; idx += 512) hbuf[0][idx] = (h16)0.f;
  {
    int r = tid >> 5, c2 = (tid & 31) * 2;
    f32x2 v = *(const f32x2*)(x + ((size_t)(b0 + r) * TSTEPS + 0) * NIN + c2);
    h16x2 pk = { (h16)v.x, (h16)v.y };
    *(h16x2*)&xbuf[0][r * XPAD + c2] = pk;
  }
  __syncthreads();

  for (int t = 0; t < TSTEPS; ++t) {
    const h16* hb = hbuf[t & 1];
    h16*       hn = hbuf[(t + 1) & 1];
    const h16* xb = xbuf[t & 1];
    h16*       xn = xbuf[(t + 1) & 1];

    if (t > 0 && wave == ((t - 1) & 7))
      out_proj(t - 1, hb, wholds, bho0, bho1, out, b0, lr, lk);

    const int tl = (t + 1 < TSTEPS) ? (t + 1) : (TSTEPS - 1);
    const int xr = tid >> 5, xc = (tid & 31) * 2;
    f32x2 xv = *(const f32x2*)(x + ((size_t)(b0 + xr) * TSTEPS + tl) * NIN + xc);

    f32x4 acc[4];
    #pragma unroll
    for (int m = 0; m < 4; ++m) acc[m] = biasv[m];
    #pragma unroll
    for (int s = 0; s < 2; ++s) {
      h16x8 bx = *(const h16x8*)&xb[lr * XPAD + s * 32 + lk * 8];
      #pragma unroll
      for (int m = 0; m < 4; ++m)
        acc[m] = __builtin_amdgcn_mfma_f32_16x16x32_f16(a_ih[m][s], bx, acc[m], 0, 0, 0);
    }
    #pragma unroll
    for (int s = 0; s < 16; ++s) {
      h16x8 bh = *(const h16x8*)&hb[lr * HPAD + s * 32 + lk * 8];
      #pragma unroll
      for (int m = 0; m < 4; ++m)
        acc[m] = __builtin_amdgcn_mfma_f32_16x16x32_f16(a_rec[m][s], bh, acc[m], 0, 0, 0);
    }
    #pragma unroll
    for (int m = 0; m < 4; ++m) {
      h16x4 hv;
      #pragma unroll
      for (int i = 0; i < 4; ++i) hv[i] = (h16)fast_tanh(acc[m][i]);
      *(h16x4*)&hn[lr * HPAD + wc0 + m * 16 + lk * 4] = hv;
    }
    {
      h16x2 pk = { (h16)xv.x, (h16)xv.y };
      *(h16x2*)&xn[xr * XPAD + xc] = pk;
    }
    __syncthreads();
  }

  if (wave == ((TSTEPS - 1) & 7))
    out_proj(TSTEPS - 1, hbuf[TSTEPS & 1], wholds, bho0, bho1, out, b0, lr, lk);
}

extern "C" void kernel_launch(void* const* d_in, const int* in_sizes, int n_in,
                              void* d_out, int out_size, void* d_ws, size_t ws_size,
                              hipStream_t stream) {
  (void)in_sizes; (void)n_in; (void)out_size;
  const float* x   = (const float*)d_in[0];
  const float* Wih = (const float*)d_in[1];
  const float* Whh = (const float*)d_in[2];
  const float* bih = (const float*)d_in[3];
  const float* bhh = (const float*)d_in[4];
  const float* Who = (const float*)d_in[5];
  const float* bho = (const float*)d_in[6];
  float* out = (float*)d_out;

  const size_t XP_BYTES = (size_t)TSTEPS * 256 * HDIM * sizeof(h16);  // 128 MiB
  if (ws_size >= XP_BYTES) {
    h16* xp = (h16*)d_ws;
    xp_gemm<<<dim3(256), dim3(512), 0, stream>>>(x, Wih, bih, bhh, xp);
    rnn_fast<<<dim3(256 / BB), dim3(512), 0, stream>>>(Whh, Who, bho, xp, out);
  } else {
    rnn_fused<<<dim3(256 / BB), dim3(512), 0, stream>>>(x, Wih, Whh, bih, bhh, Who, bho, out);
  }
}

// Round 3
// 1089.592 us; speedup vs baseline: 4.0363x; 1.7839x over previous
//
#include <hip/hip_runtime.h>
#include <cstdint>
#include <cstddef>

// RNN: B=256, T=512, H=512, I=64, O=24. fp32 in/out.
//
// v3 structure:
//  Path A (ws >= 256 MiB):
//    1) xp_gemm: xp[b][t][:] = W_ih x + b_ih + b_hh (f16, permuted) -> ws[0,128Mi)
//    2) rnn_core: persistent recurrence, 16 blocks x 8 waves, W_hh A-frags
//       49 slots in regs (196 VGPR) + 15 slots in LDS; h double-buffered in
//       LDS, ONE barrier/step; h(t) history streamed f16 -> ws[128Mi,256Mi).
//       No output projection in the loop.
//    3) out_all: full-chip epilogue, out = tanh(h_all @ W_ho^T + b_ho).
//  Path B (ws >= 128 MiB): round-2 structure + __launch_bounds__(512,2).
//  Path C: round-0 self-contained kernel.

#define TSTEPS 512
#define HDIM   512
#define NIN    64
#define NOUT   24
#define BB     16
#define HPAD   520
#define XPAD   72
// Path A split
#define NREG   49
#define NLDS   (64 - NREG)   // 15
// Path B split
#define NREG_B 50
#define NLDS_B (64 - NREG_B) // 14

typedef _Float16 h16;
typedef __attribute__((ext_vector_type(8))) _Float16 h16x8;
typedef __attribute__((ext_vector_type(4))) _Float16 h16x4;
typedef __attribute__((ext_vector_type(2))) _Float16 h16x2;
typedef __attribute__((ext_vector_type(4))) float    f32x4;
typedef __attribute__((ext_vector_type(2))) float    f32x2;

__device__ __forceinline__ float fast_tanh(float z) {
  float e = __builtin_amdgcn_exp2f(z * 2.8853900817779268f);
  return 1.0f - 2.0f * __builtin_amdgcn_rcpf(e + 1.0f);
}

__device__ __forceinline__ h16x8 cvt8(const float* __restrict__ p) {
  f32x4 f0 = *(const f32x4*)p;
  f32x4 f1 = *(const f32x4*)(p + 4);
  h16x8 a;
  #pragma unroll
  for (int j = 0; j < 4; ++j) { a[j] = (h16)f0[j]; a[4 + j] = (h16)f1[j]; }
  return a;
}

// ---------------- Prologue: xp = W_ih x + b_ih + b_hh, permuted f16 ----------
__global__ __launch_bounds__(512)
void xp_gemm(const float* __restrict__ x, const float* __restrict__ Wih,
             const float* __restrict__ bih, const float* __restrict__ bhh,
             h16* __restrict__ xp)
{
  const int tid  = threadIdx.x;
  const int wave = tid >> 6;
  const int lane = tid & 63;
  const int lr   = lane & 15;
  const int lk   = lane >> 4;
  const int blk  = blockIdx.x & 15;
  const int tc   = blockIdx.x >> 4;
  const int c0   = wave * 64;

  h16x8 A[4][2];
  #pragma unroll
  for (int m = 0; m < 4; ++m)
    #pragma unroll
    for (int s = 0; s < 2; ++s)
      A[m][s] = cvt8(Wih + (size_t)(c0 + 16 * m + lr) * NIN + 32 * s + 8 * lk);

  f32x4 bias[4];
  #pragma unroll
  for (int m = 0; m < 4; ++m) {
    const int c = c0 + 16 * m + 4 * lk;
    f32x4 bi = *(const f32x4*)&bih[c];
    f32x4 bh = *(const f32x4*)&bhh[c];
    bias[m] = bi + bh;
  }

  const float* xrow = x + (size_t)(16 * blk + lr) * (TSTEPS * NIN);

  for (int j = 0; j < 32; ++j) {
    const int t = tc * 32 + j;
    f32x4 acc[4];
    #pragma unroll
    for (int m = 0; m < 4; ++m) acc[m] = bias[m];
    #pragma unroll
    for (int s = 0; s < 2; ++s) {
      h16x8 bx = cvt8(xrow + (size_t)t * NIN + 32 * s + 8 * lk);
      #pragma unroll
      for (int m = 0; m < 4; ++m)
        acc[m] = __builtin_amdgcn_mfma_f32_16x16x32_f16(A[m][s], bx, acc[m], 0, 0, 0);
    }
    h16x8 c0v, c1v;
    #pragma unroll
    for (int i = 0; i < 4; ++i) {
      c0v[i]     = (h16)acc[0][i];
      c0v[4 + i] = (h16)acc[1][i];
      c1v[i]     = (h16)acc[2][i];
      c1v[4 + i] = (h16)acc[3][i];
    }
    h16* p = xp + ((((size_t)t * 16 + blk) * 8 + wave) * 64 + lane) * 16;
    *(h16x8*)p       = c0v;
    *(h16x8*)(p + 8) = c1v;
  }
}

// ---------------- Path A: recurrence only, h history to global ---------------
__global__ __launch_bounds__(512, 2)
void rnn_core(const float* __restrict__ Whh, const h16* __restrict__ xp,
              h16* __restrict__ hall)
{
  __shared__ h16 hbuf[2][BB * HPAD];        // 33280 B
  __shared__ h16 aslice[NLDS * 8 * 512];    // 122880 B  -> total 156160 B

  const int tid  = threadIdx.x;
  const int wave = tid >> 6;
  const int lane = tid & 63;
  const int lr   = lane & 15;
  const int lk   = lane >> 4;
  const int blk  = blockIdx.x;
  const int b0   = blk * BB;
  const int wc0  = wave * 64;

  // W_hh fragments: slot id = s*4+m; id < NREG -> regs, else LDS
  h16x8 areg[NREG];
  #pragma unroll
  for (int s = 0; s < 16; ++s) {
    #pragma unroll
    for (int m = 0; m < 4; ++m) {
      h16x8 a = cvt8(Whh + (size_t)(wc0 + 16 * m + lr) * HDIM + 32 * s + 8 * lk);
      const int id = s * 4 + m;
      if (id < NREG) areg[id] = a;
      else *(h16x8*)&aslice[(size_t)((id - NREG) * 8 + wave) * 512 + lane * 8] = a;
    }
  }

  for (int idx = tid; idx < BB * HPAD; idx += 512) hbuf[0][idx] = (h16)0.f;
  __syncthreads();

  // preload xp(0)
  h16x8 xr0, xr1;
  {
    const h16* p = xp + (((size_t)blk * 8 + wave) * 64 + lane) * 16;
    xr0 = *(const h16x8*)p;
    xr1 = *(const h16x8*)(p + 8);
  }

  for (int t = 0; t < TSTEPS; ++t) {
    const h16* hb = hbuf[t & 1];
    h16*       hn = hbuf[(t + 1) & 1];

    f32x4 acc[4];
    #pragma unroll
    for (int i = 0; i < 4; ++i) {
      acc[0][i] = (float)xr0[i];
      acc[1][i] = (float)xr0[4 + i];
      acc[2][i] = (float)xr1[i];
      acc[3][i] = (float)xr1[4 + i];
    }

    // prefetch xp(t+1)
    {
      const int tn = (t + 1 < TSTEPS) ? (t + 1) : t;
      const h16* p = xp + ((((size_t)tn * 16 + blk) * 8 + wave) * 64 + lane) * 16;
      xr0 = *(const h16x8*)p;
      xr1 = *(const h16x8*)(p + 8);
    }

    #pragma unroll
    for (int s = 0; s < 16; ++s) {
      h16x8 bh = *(const h16x8*)&hb[lr * HPAD + 32 * s + 8 * lk];
      #pragma unroll
      for (int m = 0; m < 4; ++m) {
        const int id = s * 4 + m;
        h16x8 a = (id < NREG)
            ? areg[id]
            : *(const h16x8*)&aslice[(size_t)((id - NREG) * 8 + wave) * 512 + lane * 8];
        acc[m] = __builtin_amdgcn_mfma_f32_16x16x32_f16(a, bh, acc[m], 0, 0, 0);
      }
    }

    // h_new: lane -> batch row lr, hcols wc0+16m+4lk+i
    h16* hrow = hall + ((size_t)t * 256 + b0 + lr) * HDIM + wc0 + lk * 4;
    #pragma unroll
    for (int m = 0; m < 4; ++m) {
      h16x4 hv;
      #pragma unroll
      for (int i = 0; i < 4; ++i) hv[i] = (h16)fast_tanh(acc[m][i]);
      *(h16x4*)&hn[lr * HPAD + wc0 + 16 * m + 4 * lk] = hv;
      *(h16x4*)(hrow + 16 * m) = hv;                      // history for epilogue
    }

    __syncthreads();   // hn complete before next step reads it
  }
}

// ---------------- Path A epilogue: out = tanh(h_all @ W_ho^T + b_ho) ---------
// wave tile rt = blockIdx.x*8+wave in [0,8192): t = rt>>4, batch chunk bc = rt&15.
__global__ __launch_bounds__(512)
void out_all(const h16* __restrict__ hall, const float* __restrict__ Who,
             const float* __restrict__ bho, float* __restrict__ out)
{
  __shared__ h16 wholds[NOUT * HPAD];   // 24960 B

  const int tid  = threadIdx.x;
  const int wave = tid >> 6;
  const int lane = tid & 63;
  const int lr   = lane & 15;
  const int lk   = lane >> 4;

  for (int idx = tid; idx < NOUT * HDIM; idx += 512) {
    int r = idx >> 9, k = idx & 511;
    wholds[r * HPAD + k] = (h16)Who[idx];
  }

  f32x4 o0, o1;
  { o0 = *(const f32x4*)&bho[lk * 4]; }
  { int ob = 16 + lk * 4;
    if (ob < NOUT) o1 = *(const f32x4*)&bho[ob];
    else { o1[0] = 0.f; o1[1] = 0.f; o1[2] = 0.f; o1[3] = 0.f; } }
  __syncthreads();

  const int rt = blockIdx.x * 8 + wave;
  const int t  = rt >> 4;
  const int b  = (rt & 15) * 16 + lr;
  const int row1 = (16 + lr < NOUT) ? (16 + lr) : (8 + lr);

  const h16* hrow = hall + ((size_t)t * 256 + b) * HDIM + lk * 8;

  #pragma unroll
  for (int s = 0; s < 16; ++s) {
    h16x8 bh = *(const h16x8*)(hrow + 32 * s);
    h16x8 a0 = *(const h16x8*)&wholds[lr * HPAD + s * 32 + lk * 8];
    h16x8 a1 = *(const h16x8*)&wholds[row1 * HPAD + s * 32 + lk * 8];
    o0 = __builtin_amdgcn_mfma_f32_16x16x32_f16(a0, bh, o0, 0, 0, 0);
    o1 = __builtin_amdgcn_mfma_f32_16x16x32_f16(a1, bh, o1, 0, 0, 0);
  }

  float* op = out + ((size_t)b * TSTEPS + t) * NOUT;
  f32x4 v0;
  #pragma unroll
  for (int i = 0; i < 4; ++i) v0[i] = fast_tanh(o0[i]);
  *(f32x4*)(op + lk * 4) = v0;
  if (lk < 2) {
    f32x4 v1;
    #pragma unroll
    for (int i = 0; i < 4; ++i) v1[i] = fast_tanh(o1[i]);
    *(f32x4*)(op + 16 + lk * 4) = v1;
  }
}

// ---------------- shared out_proj (paths B/C) --------------------------------
__device__ __forceinline__ void out_proj(
    int t, const h16* __restrict__ hb, const h16* __restrict__ who,
    f32x4 bho0, f32x4 bho1, float* __restrict__ out, int b0, int lr, int lk)
{
  f32x4 o0 = bho0, o1 = bho1;
  const int row1 = (16 + lr < NOUT) ? (16 + lr) : (8 + lr);
  #pragma unroll
  for (int s = 0; s < 16; ++s) {
    h16x8 bh = *(const h16x8*)&hb[lr * HPAD + s * 32 + lk * 8];
    h16x8 a0 = *(const h16x8*)&who[lr * HPAD + s * 32 + lk * 8];
    h16x8 a1 = *(const h16x8*)&who[row1 * HPAD + s * 32 + lk * 8];
    o0 = __builtin_amdgcn_mfma_f32_16x16x32_f16(a0, bh, o0, 0, 0, 0);
    o1 = __builtin_amdgcn_mfma_f32_16x16x32_f16(a1, bh, o1, 0, 0, 0);
  }
  float* op = out + ((size_t)(b0 + lr) * TSTEPS + t) * NOUT;
  f32x4 v0;
  #pragma unroll
  for (int i = 0; i < 4; ++i) v0[i] = fast_tanh(o0[i]);
  *(f32x4*)(op + lk * 4) = v0;
  if (lk < 2) {
    f32x4 v1;
    #pragma unroll
    for (int i = 0; i < 4; ++i) v1[i] = fast_tanh(o1[i]);
    *(f32x4*)(op + 16 + lk * 4) = v1;
  }
}

// ---------------- Path B: round-2 structure + explicit (512,2) ---------------
__global__ __launch_bounds__(512, 2)
void rnn_fast2(const float* __restrict__ Whh, const float* __restrict__ Who,
               const float* __restrict__ bho, const h16* __restrict__ xp,
               float* __restrict__ out)
{
  __shared__ h16 hls[BB * HPAD];
  __shared__ h16 wholds[NOUT * HPAD];
  __shared__ h16 aslice[NLDS_B * 8 * 512];

  const int tid  = threadIdx.x;
  const int wave = tid >> 6;
  const int lane = tid & 63;
  const int lr   = lane & 15;
  const int lk   = lane >> 4;
  const int blk  = blockIdx.x;
  const int b0   = blk * BB;
  const int wc0  = wave * 64;

  h16x8 areg[NREG_B];
  #pragma unroll
  for (int s = 0; s < 16; ++s) {
    #pragma unroll
    for (int m = 0; m < 4; ++m) {
      h16x8 a = cvt8(Whh + (size_t)(wc0 + 16 * m + lr) * HDIM + 32 * s + 8 * lk);
      const int id = s * 4 + m;
      if (id < NREG_B) areg[id] = a;
      else *(h16x8*)&aslice[(size_t)((id - NREG_B) * 8 + wave) * 512 + lane * 8] = a;
    }
  }

  f32x4 bho0, bho1;
  { bho0 = *(const f32x4*)&bho[lk * 4]; }
  { int ob = 16 + lk * 4;
    if (ob < NOUT) bho1 = *(const f32x4*)&bho[ob];
    else { bho1[0] = 0.f; bho1[1] = 0.f; bho1[2] = 0.f; bho1[3] = 0.f; } }

  for (int idx = tid; idx < NOUT * HDIM; idx += 512) {
    int r = idx >> 9, k = idx & 511;
    wholds[r * HPAD + k] = (h16)Who[idx];
  }
  for (int idx = tid; idx < BB * HPAD; idx += 512) hls[idx] = (h16)0.f;
  __syncthreads();

  h16x8 xr0, xr1;
  {
    const h16* p = xp + (((size_t)blk * 8 + wave) * 64 + lane) * 16;
    xr0 = *(const h16x8*)p;
    xr1 = *(const h16x8*)(p + 8);
  }

  for (int t = 0; t < TSTEPS; ++t) {
    if (t > 0 && wave == ((t - 1) & 7))
      out_proj(t - 1, hls, wholds, bho0, bho1, out, b0, lr, lk);

    f32x4 acc[4];
    #pragma unroll
    for (int i = 0; i < 4; ++i) {
      acc[0][i] = (float)xr0[i];
      acc[1][i] = (float)xr0[4 + i];
      acc[2][i] = (float)xr1[i];
      acc[3][i] = (float)xr1[4 + i];
    }
    {
      const int tn = (t + 1 < TSTEPS) ? (t + 1) : t;
      const h16* p = xp + ((((size_t)tn * 16 + blk) * 8 + wave) * 64 + lane) * 16;
      xr0 = *(const h16x8*)p;
      xr1 = *(const h16x8*)(p + 8);
    }
    #pragma unroll
    for (int s = 0; s < 16; ++s) {
      h16x8 bh = *(const h16x8*)&hls[lr * HPAD + 32 * s + 8 * lk];
      #pragma unroll
      for (int m = 0; m < 4; ++m) {
        const int id = s * 4 + m;
        h16x8 a = (id < NREG_B)
            ? areg[id]
            : *(const h16x8*)&aslice[(size_t)((id - NREG_B) * 8 + wave) * 512 + lane * 8];
        acc[m] = __builtin_amdgcn_mfma_f32_16x16x32_f16(a, bh, acc[m], 0, 0, 0);
      }
    }
    __syncthreads();
    #pragma unroll
    for (int m = 0; m < 4; ++m) {
      h16x4 hv;
      #pragma unroll
      for (int i = 0; i < 4; ++i) hv[i] = (h16)fast_tanh(acc[m][i]);
      *(h16x4*)&hls[lr * HPAD + wc0 + 16 * m + 4 * lk] = hv;
    }
    __syncthreads();
  }

  if (wave == ((TSTEPS - 1) & 7))
    out_proj(TSTEPS - 1, hls, wholds, bho0, bho1, out, b0, lr, lk);
}

// ---------------- Path C: fully self-contained fallback ----------------------
__global__ __launch_bounds__(512, 2)
void rnn_fused(const float* __restrict__ x,
               const float* __restrict__ Wih,
               const float* __restrict__ Whh,
               const float* __restrict__ bih,
               const float* __restrict__ bhh,
               const float* __restrict__ Who,
               const float* __restrict__ bho,
               float* __restrict__ out)
{
  __shared__ h16 hbuf[2][BB * HPAD];
  __shared__ h16 xbuf[2][BB * XPAD];
  __shared__ h16 wholds[NOUT * HPAD];

  const int tid  = threadIdx.x;
  const int wave = tid >> 6;
  const int lane = tid & 63;
  const int lr   = lane & 15;
  const int lk   = lane >> 4;
  const int b0   = blockIdx.x * BB;
  const int wc0  = wave * 64;

  h16x8 a_rec[4][16];
  #pragma unroll
  for (int m = 0; m < 4; ++m) {
    const int row = wc0 + m * 16 + lr;
    #pragma unroll
    for (int s = 0; s < 16; ++s)
      a_rec[m][s] = cvt8(Whh + (size_t)row * HDIM + s * 32 + lk * 8);
  }
  h16x8 a_ih[4][2];
  #pragma unroll
  for (int m = 0; m < 4; ++m) {
    const int row = wc0 + m * 16 + lr;
    #pragma unroll
    for (int s = 0; s < 2; ++s)
      a_ih[m][s] = cvt8(Wih + (size_t)row * NIN + s * 32 + lk * 8);
  }
  f32x4 biasv[4];
  #pragma unroll
  for (int m = 0; m < 4; ++m) {
    const int c = wc0 + m * 16 + lk * 4;
    f32x4 bi = *(const f32x4*)&bih[c];
    f32x4 bh2 = *(const f32x4*)&bhh[c];
    biasv[m] = bi + bh2;
  }
  f32x4 bho0, bho1;
  { bho0 = *(const f32x4*)&bho[lk * 4]; }
  { int ob = 16 + lk * 4;
    if (ob < NOUT) bho1 = *(const f32x4*)&bho[ob];
    else { bho1[0] = 0.f; bho1[1] = 0.f; bho1[2] = 0.f; bho1[3] = 0.f; } }

  for (int idx = tid; idx < NOUT * HDIM; idx += 512) {
    int r = idx >> 9, k = idx & 511;
    wholds[r * HPAD + k] = (h16)Who[idx];
  }
  for (int idx = tid; idx < BB * HPAD; idx += 512) hbuf[0][idx] = (h16)0.f;
  {
    int r = tid >> 5, c2 = (tid & 31) * 2;
    f32x2 v = *(const f32x2*)(x + ((size_t)(b0 + r) * TSTEPS + 0) * NIN + c2);
    h16x2 pk = { (h16)v.x, (h16)v.y };
    *(h16x2*)&xbuf[0][r * XPAD + c2] = pk;
  }
  __syncthreads();

  for (int t = 0; t < TSTEPS; ++t) {
    const h16* hb = hbuf[t & 1];
    h16*       hn = hbuf[(t + 1) & 1];
    const h16* xb = xbuf[t & 1];
    h16*       xn = xbuf[(t + 1) & 1];

    if (t > 0 && wave == ((t - 1) & 7))
      out_proj(t - 1, hb, wholds, bho0, bho1, out, b0, lr, lk);

    const int tl = (t + 1 < TSTEPS) ? (t + 1) : (TSTEPS - 1);
    const int xr = tid >> 5, xc = (tid & 31) * 2;
    f32x2 xv = *(const f32x2*)(x + ((size_t)(b0 + xr) * TSTEPS + tl) * NIN + xc);

    f32x4 acc[4];
    #pragma unroll
    for (int m = 0; m < 4; ++m) acc[m] = biasv[m];
    #pragma unroll
    for (int s = 0; s < 2; ++s) {
      h16x8 bx = *(const h16x8*)&xb[lr * XPAD + s * 32 + lk * 8];
      #pragma unroll
      for (int m = 0; m < 4; ++m)
        acc[m] = __builtin_amdgcn_mfma_f32_16x16x32_f16(a_ih[m][s], bx, acc[m], 0, 0, 0);
    }
    #pragma unroll
    for (int s = 0; s < 16; ++s) {
      h16x8 bh = *(const h16x8*)&hb[lr * HPAD + s * 32 + lk * 8];
      #pragma unroll
      for (int m = 0; m < 4; ++m)
        acc[m] = __builtin_amdgcn_mfma_f32_16x16x32_f16(a_rec[m][s], bh, acc[m], 0, 0, 0);
    }
    #pragma unroll
    for (int m = 0; m < 4; ++m) {
      h16x4 hv;
      #pragma unroll
      for (int i = 0; i < 4; ++i) hv[i] = (h16)fast_tanh(acc[m][i]);
      *(h16x4*)&hn[lr * HPAD + wc0 + m * 16 + lk * 4] = hv;
    }
    {
      h16x2 pk = { (h16)xv.x, (h16)xv.y };
      *(h16x2*)&xn[xr * XPAD + xc] = pk;
    }
    __syncthreads();
  }

  if (wave == ((TSTEPS - 1) & 7))
    out_proj(TSTEPS - 1, hbuf[TSTEPS & 1], wholds, bho0, bho1, out, b0, lr, lk);
}

extern "C" void kernel_launch(void* const* d_in, const int* in_sizes, int n_in,
                              void* d_out, int out_size, void* d_ws, size_t ws_size,
                              hipStream_t stream) {
  (void)in_sizes; (void)n_in; (void)out_size;
  const float* x   = (const float*)d_in[0];
  const float* Wih = (const float*)d_in[1];
  const float* Whh = (const float*)d_in[2];
  const float* bih = (const float*)d_in[3];
  const float* bhh = (const float*)d_in[4];
  const float* Who = (const float*)d_in[5];
  const float* bho = (const float*)d_in[6];
  float* out = (float*)d_out;

  const size_t XP_BYTES   = (size_t)TSTEPS * 256 * HDIM * sizeof(h16);  // 128 MiB
  const size_t HALL_BYTES = (size_t)TSTEPS * 256 * HDIM * sizeof(h16);  // 128 MiB

  if (ws_size >= XP_BYTES + HALL_BYTES) {
    h16* xp   = (h16*)d_ws;
    h16* hall = (h16*)((char*)d_ws + XP_BYTES);
    xp_gemm<<<dim3(256), dim3(512), 0, stream>>>(x, Wih, bih, bhh, xp);
    rnn_core<<<dim3(256 / BB), dim3(512), 0, stream>>>(Whh, xp, hall);
    out_all<<<dim3(1024), dim3(512), 0, stream>>>(hall, Who, bho, out);
  } else if (ws_size >= XP_BYTES) {
    h16* xp = (h16*)d_ws;
    xp_gemm<<<dim3(256), dim3(512), 0, stream>>>(x, Wih, bih, bhh, xp);
    rnn_fast2<<<dim3(256 / BB), dim3(512), 0, stream>>>(Whh, Who, bho, xp, out);
  } else {
    rnn_fused<<<dim3(256 / BB), dim3(512), 0, stream>>>(x, Wih, Whh, bih, bhh, Who, bho, out);
  }
}